// Round 3
// baseline (212.087 us; speedup 1.0000x reference)
//
#include <hip/hip_runtime.h>
#include <stdint.h>

typedef _Float16 f16;
typedef _Float16 f16x8 __attribute__((ext_vector_type(8)));
typedef float f32x4 __attribute__((ext_vector_type(4)));

#define G_SEQ   2048
#define DMODEL  256
#define NHEADS  8
#define DHEAD   32
#define BATCH   4
#define BH_TOT  32      // BATCH*NHEADS
#define M_ROWS  8192    // BATCH*G_SEQ
#define MWORDS  64      // mask words per row (2048/32)

// ---------------------------------------------------------------------------
// Mask packer with runtime dtype detection (bool-as-u8 vs int32 vs float32).
// Scans first 1024 words: 0x3F800000 => f32 ones; nonzero bytes 1..3 => u8.
// ---------------------------------------------------------------------------
__global__ __launch_bounds__(256) void pack_mask_kernel(const uint32_t* __restrict__ mraw,
                                                        uint32_t* __restrict__ bits) {
  __shared__ int s_flags;
  int t = threadIdx.x;
  if (t == 0) s_flags = 0;
  __syncthreads();
  int local = 0;
  for (int i = t; i < 1024; i += 256) {
    uint32_t x = mraw[i];
    if (x == 0x3F800000u) local |= 1;
    else if ((x & 0xFFFFFF00u) != 0u) local |= 2;
  }
  if (local) atomicOr(&s_flags, local);
  __syncthreads();
  int fl = s_flags;
  int mode = (fl & 1) ? 0 : ((fl & 2) ? 1 : 2);  // 0=f32, 1=u8, 2=i32
  int word = blockIdx.x * 256 + t;               // 131072 words total
  uint32_t out = 0;
  if (mode == 1) {
    const uint32_t* p = mraw + (size_t)word * 8; // 32 bytes
    #pragma unroll
    for (int j = 0; j < 8; ++j) {
      uint32_t v = p[j];
      if (v & 0x000000FFu) out |= 1u << (j * 4 + 0);
      if (v & 0x0000FF00u) out |= 1u << (j * 4 + 1);
      if (v & 0x00FF0000u) out |= 1u << (j * 4 + 2);
      if (v & 0xFF000000u) out |= 1u << (j * 4 + 3);
    }
  } else {
    const uint32_t* p = mraw + (size_t)word * 32; // 32 4-byte elems
    #pragma unroll
    for (int j = 0; j < 32; ++j) if (p[j] != 0u) out |= 1u << j;
  }
  bits[word] = out;
}

// ---------------------------------------------------------------------------
// Weight transpose + f32->f16: in [K][N] row-major -> out [N][K] f16.
// Tile 32x32 through LDS. Grid: (N/32, K/32), 256 threads.
// ---------------------------------------------------------------------------
__global__ __launch_bounds__(256) void wtrans_kernel(const float* __restrict__ in,
                                                     f16* __restrict__ out, int K, int N) {
  __shared__ float tile[32][33];
  int n0 = blockIdx.x * 32;
  int k0 = blockIdx.y * 32;
  int t  = threadIdx.x;
  int r  = t >> 3;          // 0..31
  int c4 = (t & 7) * 4;     // 0..28
  const float4 v = *(const float4*)(in + (size_t)(k0 + r) * N + n0 + c4);
  tile[r][c4 + 0] = v.x; tile[r][c4 + 1] = v.y;
  tile[r][c4 + 2] = v.z; tile[r][c4 + 3] = v.w;
  __syncthreads();
  #pragma unroll
  for (int i = 0; i < 4; ++i)
    out[(size_t)(n0 + r) * K + k0 + c4 + i] = (f16)tile[c4 + i][r];
}

// ---------------------------------------------------------------------------
// fp16 MFMA GEMM: C[M][N] = A[M][256] * Bt[N][256]^T + bias.
// BM=BN=64, BK=32, 256 thr = 4 waves in 2x2, wave tile 32x32 (2x2 frags).
// AF16: A already f16, else f32 (converted at staging).
// EPI 0: split into Q(,scaled)/K/V f16 (B,H,G,32).  EPI 1: f32 out + bias.
// ---------------------------------------------------------------------------
template<int AF16, int EPI>
__global__ __launch_bounds__(256) void gemm_kernel(const void* __restrict__ Aptr,
                                                   const f16* __restrict__ Bt,
                                                   const float* __restrict__ bias,
                                                   float* __restrict__ outF,
                                                   f16* __restrict__ q_out,
                                                   f16* __restrict__ k_out,
                                                   f16* __restrict__ v_out) {
  __shared__ f16 Asl[64][40];
  __shared__ f16 Bsl[64][40];
  int t = threadIdx.x;
  int lane = t & 63;
  int wv = t >> 6;
  int wm = wv >> 1, wn = wv & 1;
  int m0 = blockIdx.x * 64;
  int n0 = blockIdx.y * 64;
  int fr = lane & 15;
  int fo = (lane >> 4) * 8;

  f32x4 acc[2][2];
  #pragma unroll
  for (int i = 0; i < 2; ++i)
    #pragma unroll
    for (int j = 0; j < 2; ++j) acc[i][j] = (f32x4){0.f, 0.f, 0.f, 0.f};

  int sr = t >> 2;           // 0..63 staging row
  int sc8 = (t & 3) * 8;     // 0,8,16,24

  for (int k0 = 0; k0 < 256; k0 += 32) {
    if (AF16) {
      *(f16x8*)&Asl[sr][sc8] =
          *(const f16x8*)((const f16*)Aptr + (size_t)(m0 + sr) * 256 + k0 + sc8);
    } else {
      const float* ap = (const float*)Aptr + (size_t)(m0 + sr) * 256 + k0 + sc8;
      float4 v0 = *(const float4*)ap;
      float4 v1 = *(const float4*)(ap + 4);
      f16x8 h;
      h[0] = (f16)v0.x; h[1] = (f16)v0.y; h[2] = (f16)v0.z; h[3] = (f16)v0.w;
      h[4] = (f16)v1.x; h[5] = (f16)v1.y; h[6] = (f16)v1.z; h[7] = (f16)v1.w;
      *(f16x8*)&Asl[sr][sc8] = h;
    }
    *(f16x8*)&Bsl[sr][sc8] =
        *(const f16x8*)(Bt + (size_t)(n0 + sr) * 256 + k0 + sc8);
    __syncthreads();

    f16x8 af[2], bf[2];
    #pragma unroll
    for (int mi = 0; mi < 2; ++mi) af[mi] = *(const f16x8*)&Asl[wm * 32 + mi * 16 + fr][fo];
    #pragma unroll
    for (int ni = 0; ni < 2; ++ni) bf[ni] = *(const f16x8*)&Bsl[wn * 32 + ni * 16 + fr][fo];
    #pragma unroll
    for (int mi = 0; mi < 2; ++mi)
      #pragma unroll
      for (int ni = 0; ni < 2; ++ni)
        acc[mi][ni] = __builtin_amdgcn_mfma_f32_16x16x32_f16(af[mi], bf[ni], acc[mi][ni], 0, 0, 0);
    __syncthreads();
  }

  int rg = (lane >> 4) * 4;
  #pragma unroll
  for (int mi = 0; mi < 2; ++mi) {
    #pragma unroll
    for (int ni = 0; ni < 2; ++ni) {
      int c = n0 + wn * 32 + ni * 16 + fr;
      float bv = bias[c];
      #pragma unroll
      for (int r = 0; r < 4; ++r) {
        int m = m0 + wm * 32 + mi * 16 + rg + r;
        float val = acc[mi][ni][r] + bv;
        if (EPI == 0) {
          int which = c >> 8, h = (c >> 5) & 7, d = c & 31;
          int b = m >> 11, g = m & 2047;
          size_t off = (((size_t)(b * NHEADS + h)) * G_SEQ + g) * DHEAD + d;
          f16* dst = (which == 0) ? q_out : (which == 1) ? k_out : v_out;
          dst[off] = (f16)((which == 0) ? val * 0.17677669529663689f : val);
        } else {
          outF[(size_t)m * 256 + c] = val;
        }
      }
    }
  }
}

// ---------------------------------------------------------------------------
// Flash attention: grid (32 qblocks, 32 bh), 256 thr = 4 waves x 16 queries.
// Q pre-scaled by 1/sqrt(d). KV tiles of 64. fp16 MFMA, f32 online softmax.
// ---------------------------------------------------------------------------
__global__ __launch_bounds__(256) void attn_kernel(const f16* __restrict__ Q,
                                                   const f16* __restrict__ Kx,
                                                   const f16* __restrict__ V,
                                                   const uint32_t* __restrict__ bits,
                                                   f16* __restrict__ Y) {
  __shared__ f16 Ksl[64][40];       // padded: b128 reads ~2-way max
  __shared__ f16 Vsl[64][34];       // padded: u16 gather conflict-free
  __shared__ f16 Psl[4][16][72];    // per-wave P, padded for b128 reads

  int t = threadIdx.x;
  int lane = t & 63;
  int wv = t >> 6;
  int bh = blockIdx.y;
  int qb = blockIdx.x * 64;
  int fr = lane & 15;
  int fg = lane >> 4;

  const f16* Qb = Q + (size_t)bh * G_SEQ * DHEAD;
  const f16* Kb = Kx + (size_t)bh * G_SEQ * DHEAD;
  const f16* Vb = V + (size_t)bh * G_SEQ * DHEAD;

  // Q fragment for this wave's 16 queries (A-frag: row=lane&15, k=8*(lane>>4)+j)
  f16x8 qf = *(const f16x8*)(Qb + (size_t)(qb + wv * 16 + fr) * DHEAD + fg * 8);

  f32x4 o0 = (f32x4){0.f, 0.f, 0.f, 0.f};
  f32x4 o1 = (f32x4){0.f, 0.f, 0.f, 0.f};
  float mrow[4] = {-1e30f, -1e30f, -1e30f, -1e30f};
  float lrow[4] = {0.f, 0.f, 0.f, 0.f};
  int qrows[4];
  #pragma unroll
  for (int r = 0; r < 4; ++r) qrows[r] = qb + wv * 16 + fg * 4 + r;  // C-layout rows

  int sr = t >> 2;           // staging row 0..63
  int sc8 = (t & 3) * 8;

  for (int kv = 0; kv < G_SEQ; kv += 64) {
    // ---- stage K and V tiles ----
    *(f16x8*)&Ksl[sr][sc8] = *(const f16x8*)(Kb + (size_t)(kv + sr) * DHEAD + sc8);
    {
      f16x8 vvv = *(const f16x8*)(Vb + (size_t)(kv + sr) * DHEAD + sc8);
      uint32_t* vd = (uint32_t*)&Vsl[sr][sc8];   // 4-byte aligned (stride 68B)
      const uint32_t* ps32 = (const uint32_t*)&vvv;
      vd[0] = ps32[0]; vd[1] = ps32[1]; vd[2] = ps32[2]; vd[3] = ps32[3];
    }
    __syncthreads();

    // ---- S = Q K^T (already scaled) ----
    f32x4 s[4];
    #pragma unroll
    for (int nb = 0; nb < 4; ++nb) {
      f16x8 kf = *(const f16x8*)&Ksl[nb * 16 + fr][fg * 8];
      f32x4 z = (f32x4){0.f, 0.f, 0.f, 0.f};
      s[nb] = __builtin_amdgcn_mfma_f32_16x16x32_f16(qf, kf, z, 0, 0, 0);
    }

    // ---- mask words for my 4 rows ----
    uint32_t w0[4], w1[4];
    #pragma unroll
    for (int r = 0; r < 4; ++r) {
      w0[r] = bits[(size_t)qrows[r] * MWORDS + (kv >> 5)];
      w1[r] = bits[(size_t)qrows[r] * MWORDS + (kv >> 5) + 1];
    }

    // ---- online softmax per row ----
    float alpha[4];
    #pragma unroll
    for (int r = 0; r < 4; ++r) {
      float sv[4]; bool al[4];
      float mx = -1e30f;
      #pragma unroll
      for (int nb = 0; nb < 4; ++nb) {
        uint32_t wsel = (nb < 2) ? w0[r] : w1[r];
        al[nb] = (wsel >> ((nb & 1) * 16 + fr)) & 1u;
        sv[nb] = al[nb] ? s[nb][r] : -1e30f;
        mx = fmaxf(mx, sv[nb]);
      }
      #pragma unroll
      for (int off = 1; off < 16; off <<= 1) mx = fmaxf(mx, __shfl_xor(mx, off, 64));
      float mnew = fmaxf(mrow[r], mx);
      float a = __expf(mrow[r] - mnew);
      mrow[r] = mnew;
      float ps = 0.f;
      #pragma unroll
      for (int nb = 0; nb < 4; ++nb) {
        float p = al[nb] ? __expf(sv[nb] - mnew) : 0.f;  // predicate kills exp(0) trap
        ps += p;
        Psl[wv][fg * 4 + r][nb * 16 + fr] = (f16)p;
      }
      #pragma unroll
      for (int off = 1; off < 16; off <<= 1) ps += __shfl_xor(ps, off, 64);
      alpha[r] = a;
      lrow[r] = lrow[r] * a + ps;
    }
    #pragma unroll
    for (int r = 0; r < 4; ++r) { o0[r] *= alpha[r]; o1[r] *= alpha[r]; }

    // ---- O += P V ----
    #pragma unroll
    for (int kb = 0; kb < 2; ++kb) {
      f16x8 pa = *(const f16x8*)&Psl[wv][fr][kb * 32 + fg * 8];
      f16x8 vb0, vb1;
      #pragma unroll
      for (int j = 0; j < 8; ++j) {
        int key = kb * 32 + fg * 8 + j;
        vb0[j] = Vsl[key][fr];
        vb1[j] = Vsl[key][16 + fr];
      }
      o0 = __builtin_amdgcn_mfma_f32_16x16x32_f16(pa, vb0, o0, 0, 0, 0);
      o1 = __builtin_amdgcn_mfma_f32_16x16x32_f16(pa, vb1, o1, 0, 0, 0);
    }
    __syncthreads();
  }

  // ---- normalize + write Y f16 (B,G,256) at col h*32+d ----
  int b = bh >> 3, h = bh & 7;
  #pragma unroll
  for (int r = 0; r < 4; ++r) {
    float inv = 1.0f / lrow[r];
    size_t base = ((size_t)b * G_SEQ + qrows[r]) * DMODEL + h * DHEAD;
    Y[base + fr]      = (f16)(o0[r] * inv);
    Y[base + 16 + fr] = (f16)(o1[r] * inv);
  }
}

// ---------------------------------------------------------------------------
// Workspace layout (bytes):
//   0        maskbits   524288
//   524288   WtQKV f16  393216   (768x256)
//   917504   WtOut f16  131072   (256x256)
//   1048576  Q f16      4194304  (B,H,G,32)  pre-scaled by 1/sqrt(32)
//   5242880  K f16      4194304
//   9437184  V f16      4194304
//   13631488 Y f16      4194304  (B,G,256)
//   total 17825792
// ---------------------------------------------------------------------------
extern "C" void kernel_launch(void* const* d_in, const int* in_sizes, int n_in,
                              void* d_out, int out_size, void* d_ws, size_t ws_size,
                              hipStream_t stream) {
  const float* x      = (const float*)d_in[0];
  const uint32_t* msk = (const uint32_t*)d_in[1];
  const float* Wqkv   = (const float*)d_in[2];
  const float* bqkv   = (const float*)d_in[3];
  const float* Wout   = (const float*)d_in[4];
  const float* bout   = (const float*)d_in[5];

  char* ws = (char*)d_ws;
  uint32_t* bits = (uint32_t*)ws;
  f16* WtQ = (f16*)(ws + 524288);
  f16* WtO = (f16*)(ws + 917504);
  f16* Qf  = (f16*)(ws + 1048576);
  f16* Kf  = (f16*)(ws + 5242880);
  f16* Vf  = (f16*)(ws + 9437184);
  f16* Yf  = (f16*)(ws + 13631488);

  pack_mask_kernel<<<dim3(512), dim3(256), 0, stream>>>(msk, bits);
  wtrans_kernel<<<dim3(768 / 32, 256 / 32), dim3(256), 0, stream>>>(Wqkv, WtQ, 256, 768);
  wtrans_kernel<<<dim3(256 / 32, 256 / 32), dim3(256), 0, stream>>>(Wout, WtO, 256, 256);
  gemm_kernel<0, 0><<<dim3(128, 12), dim3(256), 0, stream>>>(x, WtQ, bqkv, nullptr, Qf, Kf, Vf);
  attn_kernel<<<dim3(32, 32), dim3(256), 0, stream>>>(Qf, Kf, Vf, bits, Yf);
  gemm_kernel<1, 1><<<dim3(128, 4), dim3(256), 0, stream>>>(Yf, WtO, bout, (float*)d_out,
                                                            nullptr, nullptr, nullptr);
}